// Round 3
// baseline (197.913 us; speedup 1.0000x reference)
//
#include <hip/hip_runtime.h>
#include <hip/hip_bf16.h>

#define NB 256
#define IN_F 16
#define HID 64
#define NGP 4
#define PW 68   // xcb row stride (floats); 16B-aligned rows, broadcast reads

// ---------------- compile-time algebra tables ----------------
namespace alg {
constexpr int popc(int x){int c=0;while(x){c+=x&1;x>>=1;}return c;}
struct Tables {
  int qt[64];
  int perm[64];
  int inv[64];
  unsigned char kslot[64][64];// [j_slot][i_slot] -> k_slot
  unsigned char widx [64][64];// [j_slot][i_slot] -> qt_i*16+qt_j*4+qt_k
  unsigned char sgn  [64][64];
};
constexpr Tables build(){
  Tables t{};
  int mask[64]={}; int pos[64]={};
  int idx=0;
  for(int pc=0;pc<=6;++pc) for(int m=0;m<64;++m) if(popc(m)==pc) mask[idx++]=m;
  for(int i=0;i<64;++i) pos[mask[i]]=i;
  for(int i=0;i<64;++i) t.qt[i]=popc(mask[i])&3;
  int s=0;
  for(int c=0;c<4;++c) for(int i=0;i<64;++i) if(t.qt[i]==c){t.perm[s]=i;t.inv[i]=s;++s;}
  for(int js=0;js<64;++js) for(int is=0;is<64;++is){
    int oi=t.perm[is], oj=t.perm[js];
    int mk=mask[oi]^mask[oj];
    int ok=pos[mk];
    t.kslot[js][is]=(unsigned char)t.inv[ok];
    t.widx [js][is]=(unsigned char)(t.qt[oi]*16+t.qt[oj]*4+t.qt[ok]);
    int scnt=0, tt=mask[oi]>>1;
    while(tt){scnt+=popc(tt&mk);tt>>=1;}
    t.sgn[js][is]=(unsigned char)(scnt&1);
  }
  return t;
}
constexpr Tables T = build();
// class-contiguous slot ranges: sizes 16,12,16,20
constexpr int CLS_BEG[4] = {0,16,28,44};
constexpr int CLS_END[4] = {16,28,44,64};
}

// ---------------- prep: transpose weights into workspace ----------------
// lw_t[((l*4+c)*64+m)*64+f] = gp_lin_w[((l*64+f)*64+m)*4+c]   (65536 floats)
// gpw_t[(l*64+k)*64+f]      = gp_w[(l*64+f)*64+k]             (16384 floats)
// w1t [f2*64+f]             = mlp_w1[f*64+f2]                 ( 4096 floats)
__global__ void ga_prep(const float* __restrict__ gp_lin_w,
                        const float* __restrict__ gp_w,
                        const float* __restrict__ mlp_w1,
                        float* __restrict__ lw_t, float* __restrict__ gpw_t,
                        float* __restrict__ w1t,
                        float* __restrict__ out) {
  const int bx = blockIdx.x, t = threadIdx.x;
  if (bx == 0 && t == 0) out[0] = 0.f;   // mean accumulator init
  if (bx < 256) {
    int o = bx*256 + t;
    int f = o & 63, m = (o>>6)&63, c = (o>>12)&3, l = (o>>14)&3;
    lw_t[o] = gp_lin_w[((l*64+f)*64+m)*4 + c];
  } else if (bx < 320) {
    int o = (bx-256)*256 + t;
    int f = o & 63, k = (o>>6)&63, l = (o>>12)&3;
    gpw_t[o] = gp_w[(l*64+f)*64 + k];
  } else {
    int o = (bx-320)*256 + t;          // 16 blocks * 256 = 4096
    int f = o & 63, f2 = o >> 6;
    w1t[o] = mlp_w1[f*64 + f2];
  }
}

// ---------------- GP body: 4 j-slots, fully unrolled vs constexpr tables ----
template<int JQ>
__device__ __forceinline__ void gp_body4(const float* __restrict__ xbcf,
    const float (&y)[64], const float (&w)[16], float (&acc)[4]) {
  #pragma unroll
  for (int is = 0; is < 64; ++is) {
    const float xi = xbcf[is*64];
    #pragma unroll
    for (int jj = 0; jj < 4; ++jj) {
      const int js = JQ*4 + jj;
      const int k  = alg::T.kslot[js][is];
      const int wi = alg::T.widx [js][is];
      const int w16i = ((wi>>4)<<2) | (wi&3);    // qi*4 + qk (qj fixed per JQ)
      const float tp = w[w16i] * y[k];
      acc[jj] = alg::T.sgn[js][is] ? fmaf(-tp, xi, acc[jj])
                                   : fmaf( tp, xi, acc[jj]);
    }
  }
}

// ---------------- main fused kernel: one block (1024 thr) per batch element ----
// amdgpu_waves_per_eu(4,4): launch shape is 1 block/CU * 16 waves = exactly
// 4 waves/EU. Without this the backend budgets VGPRs for the LDS-derived
// occupancy (2 blocks/CU -> 8 waves/EU -> 64 VGPR) and spills ~300MB/dispatch.
__global__ __attribute__((amdgpu_flat_work_group_size(1024,1024)))
__attribute__((amdgpu_waves_per_eu(4,4)))
void ga_main(
    const float* __restrict__ points, const float* __restrict__ products,
    const float* __restrict__ lin_w,  const float* __restrict__ lin_b,
    const float* __restrict__ gp_a,
    const float* __restrict__ mlp_b1,
    const float* __restrict__ mlp_w2, const float* __restrict__ mlp_b2,
    const float* __restrict__ lw_t,   const float* __restrict__ gpw_t,
    const float* __restrict__ w1t,
    float* __restrict__ d_out)
{
  __shared__ __align__(16) float xcb[64*PW];   // [channel][blade-slot]
  __shared__ float xbc[64*64];                 // [blade-slot][channel]
  __shared__ float ybc[64*64];                 // [blade-slot][channel]
  __shared__ float invn[4*64];                 // [class][channel]
  __shared__ float red[16*64];                 // [jq][channel] partials
  __shared__ float pts[96];
  __shared__ float ynrm[64];

  const int t  = threadIdx.x;
  const int b  = blockIdx.x;
  const int f  = t & 63;
  const int jq = t >> 6;                       // 0..15, wave-uniform
  const int c  = (jq>=4) + (jq>=7) + (jq>=11); // class of this thread's 4 slots

  for (int i = t; i < 64*PW; i += 1024) xcb[i] = 0.f;
  for (int i = t; i < 64*64; i += 1024) xbc[i] = 0.f;
  if (t < 96) pts[t] = points[b*96 + t];
  __syncthreads();

  // phase 0: embed grade-1 + first qt-linear
  if (t < 64) {
    float a[6] = {0,0,0,0,0,0};
    for (int m = 0; m < IN_F; ++m) {
      float lw = lin_w[(t*IN_F+m)*4 + 1];   // qt(grade1)=1
      #pragma unroll
      for (int g = 0; g < 6; ++g) a[g] = fmaf(pts[m*6+g], lw, a[g]);
    }
    float bias = lin_b[t];
    xcb[t*PW + 0] = bias; xbc[0*64 + t] = bias;
    #pragma unroll
    for (int g = 0; g < 6; ++g) {
      xcb[t*PW + 16+g] = a[g];
      xbc[(16+g)*64 + t] = a[g];
    }
  }
  __syncthreads();

  float gacc[4];

  for (int l = 0; l < NGP; ++l) {
    // ---- qt-linear: 4 outputs/thread, single class, broadcast x reads ----
    float lacc[4] = {0.f,0.f,0.f,0.f};
    {
      const float* lw = lw_t + ((l*4+c)*64)*64 + f;
      const float* xr = xcb + jq*4;
      #pragma unroll 8
      for (int m = 0; m < 64; ++m) {
        const float  wv = lw[m*64];
        const float4 x4 = *(const float4*)(xr + m*PW);
        lacc[0] = fmaf(wv, x4.x, lacc[0]);
        lacc[1] = fmaf(wv, x4.y, lacc[1]);
        lacc[2] = fmaf(wv, x4.z, lacc[2]);
        lacc[3] = fmaf(wv, x4.w, lacc[3]);
      }
    }
    #pragma unroll
    for (int ii=0;ii<4;++ii) ybc[(jq*4+ii)*64 + f] = lacc[ii];
    __syncthreads();

    // ---- per-(channel,class) norms -> folded inverse scales (waves 0-3) ----
    if (t < 256) {
      const int cc = t >> 6;
      float s = 0.f;
      for (int i = alg::CLS_BEG[cc]; i < alg::CLS_END[cc]; ++i) {
        float v = ybc[i*64+f]; s = fmaf(v,v,s);
      }
      s = fmaxf(s, 1e-12f);
      float nrm = sqrtf(s);
      float av  = gp_a[(l*64+f)*4 + cc];
      float sig = 1.f/(1.f + expf(-av));
      float nn  = sig*(nrm-1.f) + 1.f;
      invn[cc*64+f] = 1.f/(nn + 1e-6f);
    }
    __syncthreads();

    // ---- geometric product ----
    float yreg[64];
    #pragma unroll
    for (int k=0;k<64;++k) yreg[k] = ybc[k*64+f];
    float w16[16];
    {
      const float in0 = invn[0*64+f], in1 = invn[1*64+f],
                  in2 = invn[2*64+f], in3 = invn[3*64+f];
      const float* wrow = gpw_t + l*4096 + f;   // [widx][f], coalesced
      #pragma unroll
      for (int qi=0;qi<4;++qi) {
        w16[qi*4+0] = wrow[(qi*16 + c*4 + 0)*64] * in0;
        w16[qi*4+1] = wrow[(qi*16 + c*4 + 1)*64] * in1;
        w16[qi*4+2] = wrow[(qi*16 + c*4 + 2)*64] * in2;
        w16[qi*4+3] = wrow[(qi*16 + c*4 + 3)*64] * in3;
      }
    }
    #pragma unroll
    for (int ii=0;ii<4;++ii) gacc[ii]=0.f;
    {
      const float* xbcf = xbc + f;
      switch (jq) {
        case  0: gp_body4< 0>(xbcf, yreg, w16, gacc); break;
        case  1: gp_body4< 1>(xbcf, yreg, w16, gacc); break;
        case  2: gp_body4< 2>(xbcf, yreg, w16, gacc); break;
        case  3: gp_body4< 3>(xbcf, yreg, w16, gacc); break;
        case  4: gp_body4< 4>(xbcf, yreg, w16, gacc); break;
        case  5: gp_body4< 5>(xbcf, yreg, w16, gacc); break;
        case  6: gp_body4< 6>(xbcf, yreg, w16, gacc); break;
        case  7: gp_body4< 7>(xbcf, yreg, w16, gacc); break;
        case  8: gp_body4< 8>(xbcf, yreg, w16, gacc); break;
        case  9: gp_body4< 9>(xbcf, yreg, w16, gacc); break;
        case 10: gp_body4<10>(xbcf, yreg, w16, gacc); break;
        case 11: gp_body4<11>(xbcf, yreg, w16, gacc); break;
        case 12: gp_body4<12>(xbcf, yreg, w16, gacc); break;
        case 13: gp_body4<13>(xbcf, yreg, w16, gacc); break;
        case 14: gp_body4<14>(xbcf, yreg, w16, gacc); break;
        default: gp_body4<15>(xbcf, yreg, w16, gacc); break;
      }
    }
    __syncthreads();           // all xbc reads done before overwrite
    if (l < NGP-1) {
      #pragma unroll
      for (int ii=0;ii<4;++ii) {
        const int s = jq*4+ii;
        xcb[f*PW + s]  = gacc[ii];
        xbc[s*64 + f]  = gacc[ii];
      }
      __syncthreads();
    }
  }

  // ---- tail: blade-norm -> MLP -> loss ----
  float ss = 0.f;
  #pragma unroll
  for (int ii=0;ii<4;++ii) ss = fmaf(gacc[ii],gacc[ii],ss);
  red[jq*64+f] = ss;
  __syncthreads();
  if (t < 64) {
    float s = 0.f;
    #pragma unroll
    for (int q=0;q<16;++q) s += red[q*64+t];
    ynrm[t] = sqrtf(s);
  }
  __syncthreads();
  {
    float hp = 0.f;
    #pragma unroll
    for (int ii=0;ii<4;++ii) {
      const int f2 = jq*4+ii;
      hp = fmaf(w1t[f2*64+f], ynrm[f2], hp);   // coalesced (transposed)
    }
    red[jq*64+f] = hp;
  }
  __syncthreads();
  if (t < 64) {
    float hpre = mlp_b1[t];
    #pragma unroll
    for (int q=0;q<16;++q) hpre += red[q*64+t];
    float h = hpre / (1.f + expf(-hpre));   // silu
    float p = h * mlp_w2[t];
    #pragma unroll
    for (int off = 32; off > 0; off >>= 1) p += __shfl_down(p, off, 64);
    if (t == 0) {
      float pred = p + mlp_b2[0];
      float d = pred - products[b];
      float loss = d*d;
      d_out[1+b] = loss;
      atomicAdd(d_out, loss * (1.f/256.f));
    }
  }
}

extern "C" void kernel_launch(void* const* d_in, const int* in_sizes, int n_in,
                              void* d_out, int out_size, void* d_ws, size_t ws_size,
                              hipStream_t stream) {
  const float* points   = (const float*)d_in[0];
  const float* products = (const float*)d_in[1];
  const float* lin_w    = (const float*)d_in[2];
  const float* lin_b    = (const float*)d_in[3];
  const float* gp_lin_w = (const float*)d_in[4];
  const float* gp_a     = (const float*)d_in[5];
  const float* gp_w     = (const float*)d_in[6];
  const float* mlp_w1   = (const float*)d_in[7];
  const float* mlp_b1   = (const float*)d_in[8];
  const float* mlp_w2   = (const float*)d_in[9];
  const float* mlp_b2   = (const float*)d_in[10];
  float* out = (float*)d_out;

  float* lw_t  = (float*)d_ws;        // 65536 floats
  float* gpw_t = lw_t + 65536;        // 16384 floats
  float* w1t   = gpw_t + 16384;       //  4096 floats

  ga_prep<<<336, 256, 0, stream>>>(gp_lin_w, gp_w, mlp_w1, lw_t, gpw_t, w1t, out);
  ga_main<<<NB, 1024, 0, stream>>>(points, products, lin_w, lin_b, gp_a,
                                   mlp_b1, mlp_w2, mlp_b2,
                                   lw_t, gpw_t, w1t, out);
}

// Round 4
// 126.336 us; speedup vs baseline: 1.5666x; 1.5666x over previous
//
#include <hip/hip_runtime.h>

#define NB 256
#define IN_F 16
#define NGP 4

// ---------------- compile-time algebra tables (NATURAL blade order: idx=mask) ----
namespace alg {
constexpr int popc(int x){int c=0;while(x){c+=x&1;x>>=1;}return c;}
constexpr int qt(int m){return popc(m)&3;}
constexpr int sgn(int a,int b){int s=0;int t=a>>1;while(t){s+=popc(t&b);t>>=1;}return s&1;}
struct Tab {
  unsigned char w[64][64];   // [i][j] -> qt(i)*16 + qt(j)*4 + qt(i^j)
  unsigned char s[64][64];   // [i][j] -> sign of e_i * e_(i^j)
};
constexpr Tab build(){
  Tab t{};
  for(int i=0;i<64;++i)for(int j=0;j<64;++j){
    int k=i^j;
    t.w[i][j]=(unsigned char)(qt(i)*16+qt(j)*4+qt(k));
    t.s[i][j]=(unsigned char)sgn(i,k);
  }
  return t;
}
constexpr Tab T = build();
}

// ---------------- prep: transpose weights into workspace ----------------
// lw_t[((l*4+c)*64+m)*64+f] = gp_lin_w[((l*64+f)*64+m)*4+c]   (65536 floats)
// gpw_t[(l*64+widx)*64+f]   = gp_w[(l*64+f)*64+widx]          (16384 floats)
// w1t [f2*64+f]             = mlp_w1[f*64+f2]                 ( 4096 floats)
__global__ void ga_prep(const float* __restrict__ gp_lin_w,
                        const float* __restrict__ gp_w,
                        const float* __restrict__ mlp_w1,
                        float* __restrict__ lw_t, float* __restrict__ gpw_t,
                        float* __restrict__ w1t,
                        float* __restrict__ out) {
  const int bx = blockIdx.x, t = threadIdx.x;
  if (bx == 0 && t == 0) out[0] = 0.f;   // mean accumulator init
  if (bx < 256) {
    int o = bx*256 + t;
    int f = o & 63, m = (o>>6)&63, c = (o>>12)&3, l = (o>>14)&3;
    lw_t[o] = gp_lin_w[((l*64+f)*64+m)*4 + c];
  } else if (bx < 320) {
    int o = (bx-256)*256 + t;
    int f = o & 63, k = (o>>6)&63, l = (o>>12)&3;
    gpw_t[o] = gp_w[(l*64+f)*64 + k];
  } else {
    int o = (bx-320)*256 + t;
    int f = o & 63, f2 = o >> 6;
    w1t[o] = mlp_w1[f*64 + f2];
  }
}

// ---------------- GP: thread owns j-octet 8*JO..8*JO+7; all indices static ----
// x4/y4 layout: [quad q][channel f][sub s] = blade 4q+s of channel f.
template<int JO>
__device__ __forceinline__ void gp8(const float* __restrict__ x4,
                                    const float* __restrict__ y4,
                                    const float (&wv)[64], int f, float (&acc)[8]) {
  #pragma unroll
  for (int ic = 0; ic < 16; ++ic) {
    const float4 xv = *(const float4*)(x4 + (ic*64 + f)*4);
    const int r0 = ic ^ (2*JO);          // k-quad for j-quad h=0 (static)
    const float4 y0 = *(const float4*)(y4 + ( r0    *64 + f)*4);
    const float4 y1 = *(const float4*)(y4 + ((r0^1)*64 + f)*4);
    const float xa[4] = {xv.x, xv.y, xv.z, xv.w};
    const float ya[2][4] = {{y0.x,y0.y,y0.z,y0.w},{y1.x,y1.y,y1.z,y1.w}};
    #pragma unroll
    for (int h = 0; h < 2; ++h) {
      #pragma unroll
      for (int b = 0; b < 4; ++b) {
        const int j = 8*JO + 4*h + b;
        #pragma unroll
        for (int a = 0; a < 4; ++a) {
          const int i  = 4*ic + a;
          const int wi = alg::T.w[i][j];
          const float tp = wv[wi] * ya[h][a^b];
          acc[4*h+b] = alg::T.s[i][j] ? fmaf(-tp, xa[a], acc[4*h+b])
                                      : fmaf( tp, xa[a], acc[4*h+b]);
        }
      }
    }
  }
}

// ---------------- main fused kernel: one 512-thread block per batch element ----
// LDS deliberately padded to ~55 KB: the backend budgets VGPRs for the
// LDS-limited occupancy (measured R1/R2/R3). 55 KB @512thr -> 2 blocks/CU
// target -> 4 waves/EU -> 128-VGPR budget (64 KB+ would fail to launch;
// <53.4 KB would budget 85 VGPR and spill).
__global__ __launch_bounds__(512) void ga_main(
    const float* __restrict__ points, const float* __restrict__ products,
    const float* __restrict__ lin_w,  const float* __restrict__ lin_b,
    const float* __restrict__ gp_a,
    const float* __restrict__ mlp_b1,
    const float* __restrict__ mlp_w2, const float* __restrict__ mlp_b2,
    const float* __restrict__ lw_t,   const float* __restrict__ gpw_t,
    const float* __restrict__ w1t,
    float* __restrict__ d_out)
{
  __shared__ __align__(16) float x4[16*64*4];  // state,  [quad][f][sub]
  __shared__ __align__(16) float y4[16*64*4];  // lin out,[quad][f][sub]
  __shared__ float red[4*8*64];                // [class][jo][f] partials
  __shared__ float invn[4*64];                 // [class][f]
  __shared__ float pts[96];
  __shared__ float ynrm[64];
  __shared__ float pad_lds[3072];              // occupancy shaping (see above)

  const int t  = threadIdx.x;
  const int b  = blockIdx.x;
  const int f  = t & 63;
  const int jo = t >> 6;                       // 0..7, wave-uniform
  const int qb = __builtin_popcount((unsigned)jo) & 3;

  { volatile float* vp = pad_lds; vp[t] = 0.f; }  // keep pad allocated

  for (int i = t; i < 16*64*4; i += 512) x4[i] = 0.f;
  if (t < 96) pts[t] = points[b*96 + t];
  __syncthreads();

  // phase 0: embed grade-1 + first qt-linear (blades {0,1,2,4,8,16,32} nonzero)
  if (t < 64) {
    float a[6] = {0,0,0,0,0,0};
    for (int m = 0; m < IN_F; ++m) {
      float lw = lin_w[(t*IN_F+m)*4 + 1];   // qt(grade1)=1
      #pragma unroll
      for (int g = 0; g < 6; ++g) a[g] = fmaf(pts[m*6+g], lw, a[g]);
    }
    x4[(0*64+t)*4+0] = lin_b[t];   // blade 0
    x4[(0*64+t)*4+1] = a[0];       // blade 1
    x4[(0*64+t)*4+2] = a[1];       // blade 2
    x4[(1*64+t)*4+0] = a[2];       // blade 4
    x4[(2*64+t)*4+0] = a[3];       // blade 8
    x4[(4*64+t)*4+0] = a[4];       // blade 16
    x4[(8*64+t)*4+0] = a[5];       // blade 32
  }
  __syncthreads();

  float acc[8];

  for (int l = 0; l < NGP; ++l) {
    // ---- qt-linear: 8 outputs/thread (j = 8*jo+d); classes qb+{0,1,1,2,1,2,2,3}
    float lacc[8] = {0,0,0,0,0,0,0,0};
    {
      const float* pA = lw_t + (l*4 + ((qb+0)&3))*4096 + f;
      const float* pB = lw_t + (l*4 + ((qb+1)&3))*4096 + f;
      const float* pC = lw_t + (l*4 + ((qb+2)&3))*4096 + f;
      const float* pD = lw_t + (l*4 + ((qb+3)&3))*4096 + f;
      #pragma unroll 8
      for (int m = 0; m < 64; ++m) {
        const float4 xq0 = *(const float4*)(x4 + ((2*jo  )*64 + m)*4); // broadcast
        const float4 xq1 = *(const float4*)(x4 + ((2*jo+1)*64 + m)*4); // broadcast
        const float wA = pA[m*64], wB = pB[m*64], wC = pC[m*64], wD = pD[m*64];
        lacc[0] = fmaf(wA, xq0.x, lacc[0]);
        lacc[1] = fmaf(wB, xq0.y, lacc[1]);
        lacc[2] = fmaf(wB, xq0.z, lacc[2]);
        lacc[3] = fmaf(wC, xq0.w, lacc[3]);
        lacc[4] = fmaf(wB, xq1.x, lacc[4]);
        lacc[5] = fmaf(wC, xq1.y, lacc[5]);
        lacc[6] = fmaf(wC, xq1.z, lacc[6]);
        lacc[7] = fmaf(wD, xq1.w, lacc[7]);
      }
    }
    // y-store (b128) + per-class norm partials
    *(float4*)(y4 + ((2*jo  )*64 + f)*4) = make_float4(lacc[0],lacc[1],lacc[2],lacc[3]);
    *(float4*)(y4 + ((2*jo+1)*64 + f)*4) = make_float4(lacc[4],lacc[5],lacc[6],lacc[7]);
    red[((qb+0)&3)*512 + jo*64 + f] = lacc[0]*lacc[0];
    red[((qb+1)&3)*512 + jo*64 + f] = lacc[1]*lacc[1] + lacc[2]*lacc[2] + lacc[4]*lacc[4];
    red[((qb+2)&3)*512 + jo*64 + f] = lacc[3]*lacc[3] + lacc[5]*lacc[5] + lacc[6]*lacc[6];
    red[((qb+3)&3)*512 + jo*64 + f] = lacc[7]*lacc[7];
    __syncthreads();

    // ---- norms -> folded inverse scales ----
    if (t < 256) {
      const int cc = t >> 6, ff = t & 63;
      float s = 0.f;
      #pragma unroll
      for (int q = 0; q < 8; ++q) s += red[cc*512 + q*64 + ff];
      s = fmaxf(s, 1e-12f);
      float nrm = sqrtf(s);
      float av  = gp_a[(l*64+ff)*4 + cc];
      float sig = 1.f/(1.f + expf(-av));
      float nn  = sig*(nrm-1.f) + 1.f;
      invn[cc*64+ff] = 1.f/(nn + 1e-6f);
    }
    __syncthreads();

    // ---- fold norm scales into the per-f Cayley weight table (64 regs) ----
    float wv[64];
    {
      const float in0 = invn[0*64+f], in1 = invn[1*64+f],
                  in2 = invn[2*64+f], in3 = invn[3*64+f];
      const float* gw = gpw_t + l*4096 + f;   // [widx][f], coalesced
      #pragma unroll
      for (int wi = 0; wi < 64; ++wi) {
        const float sc = ((wi&3)==0)?in0:(((wi&3)==1)?in1:(((wi&3)==2)?in2:in3));
        wv[wi] = gw[wi*64] * sc;
      }
    }

    // ---- geometric product (all-static via jo-template) ----
    #pragma unroll
    for (int ii = 0; ii < 8; ++ii) acc[ii] = 0.f;
    switch (jo) {
      case 0: gp8<0>(x4, y4, wv, f, acc); break;
      case 1: gp8<1>(x4, y4, wv, f, acc); break;
      case 2: gp8<2>(x4, y4, wv, f, acc); break;
      case 3: gp8<3>(x4, y4, wv, f, acc); break;
      case 4: gp8<4>(x4, y4, wv, f, acc); break;
      case 5: gp8<5>(x4, y4, wv, f, acc); break;
      case 6: gp8<6>(x4, y4, wv, f, acc); break;
      default: gp8<7>(x4, y4, wv, f, acc); break;
    }
    __syncthreads();           // all x4/y4 reads done before overwrite
    if (l < NGP-1) {
      *(float4*)(x4 + ((2*jo  )*64 + f)*4) = make_float4(acc[0],acc[1],acc[2],acc[3]);
      *(float4*)(x4 + ((2*jo+1)*64 + f)*4) = make_float4(acc[4],acc[5],acc[6],acc[7]);
    }
    __syncthreads();
  }

  // ---- tail: blade-norm -> MLP -> loss ----
  float ss = 0.f;
  #pragma unroll
  for (int ii = 0; ii < 8; ++ii) ss = fmaf(acc[ii], acc[ii], ss);
  red[jo*64+f] = ss;
  __syncthreads();
  if (t < 64) {
    float s = 0.f;
    #pragma unroll
    for (int q = 0; q < 8; ++q) s += red[q*64+t];
    ynrm[t] = sqrtf(s);
  }
  __syncthreads();
  {
    float hp = 0.f;
    #pragma unroll
    for (int d = 0; d < 8; ++d) {
      const int f2 = 8*jo + d;
      hp = fmaf(w1t[f2*64+f], ynrm[f2], hp);   // coalesced (transposed)
    }
    red[jo*64+f] = hp;
  }
  __syncthreads();
  if (t < 64) {
    float hpre = mlp_b1[t];
    #pragma unroll
    for (int q = 0; q < 8; ++q) hpre += red[q*64+t];
    float h = hpre / (1.f + expf(-hpre));   // silu
    float p = h * mlp_w2[t];
    #pragma unroll
    for (int off = 32; off > 0; off >>= 1) p += __shfl_down(p, off, 64);
    if (t == 0) {
      float pred = p + mlp_b2[0];
      float d = pred - products[b];
      float loss = d*d;
      d_out[1+b] = loss;
      atomicAdd(d_out, loss * (1.f/256.f));
    }
  }
}

extern "C" void kernel_launch(void* const* d_in, const int* in_sizes, int n_in,
                              void* d_out, int out_size, void* d_ws, size_t ws_size,
                              hipStream_t stream) {
  const float* points   = (const float*)d_in[0];
  const float* products = (const float*)d_in[1];
  const float* lin_w    = (const float*)d_in[2];
  const float* lin_b    = (const float*)d_in[3];
  const float* gp_lin_w = (const float*)d_in[4];
  const float* gp_a     = (const float*)d_in[5];
  const float* gp_w     = (const float*)d_in[6];
  const float* mlp_w1   = (const float*)d_in[7];
  const float* mlp_b1   = (const float*)d_in[8];
  const float* mlp_w2   = (const float*)d_in[9];
  const float* mlp_b2   = (const float*)d_in[10];
  float* out = (float*)d_out;

  float* lw_t  = (float*)d_ws;        // 65536 floats
  float* gpw_t = lw_t + 65536;        // 16384 floats
  float* w1t   = gpw_t + 16384;       //  4096 floats

  ga_prep<<<336, 256, 0, stream>>>(gp_lin_w, gp_w, mlp_w1, lw_t, gpw_t, w1t, out);
  ga_main<<<NB, 512, 0, stream>>>(points, products, lin_w, lin_b, gp_a,
                                  mlp_b1, mlp_w2, mlp_b2,
                                  lw_t, gpw_t, w1t, out);
}